// Round 5
// baseline (424.105 us; speedup 1.0000x reference)
//
#include <hip/hip_runtime.h>

#define BSZ   16
#define LSEQ  4096
#define HCH   128
#define NST   64
#define NOUTD 128
#define TCH   64
#define NCHK  64

typedef unsigned long long u64;

// workspace float offsets
#define OFF_XT 0ull
#define OFF_U  8388608ull          // aliased as zT after the scan
#define OFF_S  16777216ull
#define OFF_G  25165824ull
#define OFF_M  25690112ull
#define OFF_P  26214400ull
#define OFF_K  26738688ull
#define OFF_WT 26746880ull
// total = 26763264 floats = 107,053,056 bytes

// ---------------- K0: transpose x[b][l][h] -> xT[b][h][l] ----------------
__global__ __launch_bounds__(256) void k_tr_x(const float* __restrict__ x, float* __restrict__ xT){
  __shared__ float tile[64][65];
  int l0 = blockIdx.x*64, h0 = blockIdx.y*64, b = blockIdx.z;
  int tid = threadIdx.x;
  int tl = tid>>6, th = tid&63;
  #pragma unroll
  for (int k=0;k<16;k++){
    int l = tl + k*4;
    tile[l][th] = x[((u64)b*LSEQ + l0+l)*HCH + h0+th];
  }
  __syncthreads();
  #pragma unroll
  for (int k=0;k<16;k++){
    int hh = tl + k*4;
    xT[((u64)b*HCH + h0+hh)*LSEQ + l0+th] = tile[th][hh];
  }
}

// ---------------- K0b: transpose W[o][h] -> Wt[h][o] ----------------
__global__ __launch_bounds__(256) void k_tr_w(const float* __restrict__ W, float* __restrict__ Wt){
  int idx = blockIdx.x*256 + threadIdx.x;   // 0..16383
  int o = idx >> 7, h = idx & 127;
  Wt[h*NOUTD + o] = W[o*HCH + h];
}

// ---------------- K1: per-channel precompute ----------------
// A_bar (fwd subst, lower-tri), B_bar = 0.5*dt*(A_bar+I)*Bm[h],
// G[t][n] = (A_bar^{63-t} B_bar)[n], ks[j] = C.A_bar^j.B_bar,
// M[t][n] = (C A_bar^{t+1})[n], P = A_bar^64 (6 squarings)
__global__ __launch_bounds__(64) void k_pre(const float* __restrict__ A, const float* __restrict__ Bm,
                   const float* __restrict__ Cm, const float* __restrict__ log_dt,
                   float* __restrict__ G, float* __restrict__ Mx,
                   float* __restrict__ P, float* __restrict__ ks){
  __shared__ __align__(16) float Lh[64][64];
  __shared__ __align__(16) float Ab[64][64];
  __shared__ __align__(16) float Tb[64][64];
  __shared__ __align__(16) float vbuf[64];
  __shared__ __align__(16) float wbuf[64];
  const int h = blockIdx.x, t = threadIdx.x;
  const float dt = expf(log_dt[h]);

  for (int j=0;j<64;j++){
    float a = A[t*64+j];
    Lh[t][j] = ((t==j)?1.f:0.f) - 0.5f*dt*a;
  }
  __syncthreads();

  // forward substitution, column t of A_bar; rhs = 2I - lhs
  float y[64];
  #pragma unroll
  for (int i=0;i<64;i++){
    float acc = ((i==t)?2.f:0.f) - Lh[i][t];
    #pragma unroll
    for (int j=0;j<i;j++) acc -= Lh[i][j]*y[j];
    y[i] = acc / Lh[i][i];
  }
  #pragma unroll
  for (int i=0;i<64;i++) Ab[i][t] = y[i];
  __syncthreads();

  // row t of A_bar into registers (for v-iteration)
  float rowr[64];
  #pragma unroll
  for (int j4=0;j4<16;j4++){
    float4 r4 = *(const float4*)&Ab[t][j4*4];
    rowr[j4*4+0]=r4.x; rowr[j4*4+1]=r4.y; rowr[j4*4+2]=r4.z; rowr[j4*4+3]=r4.w;
  }

  // B_bar
  vbuf[t] = Bm[h*NST + t];
  __syncthreads();
  float accb = vbuf[t];
  #pragma unroll
  for (int j=0;j<64;j++) accb += rowr[j]*vbuf[j];
  float vreg = 0.5f*dt*accb;          // v_0 = B_bar[t]
  const float cv = Cm[h*NST + t];

  // v-iteration: G and ks
  for (int j=0;j<64;j++){
    __syncthreads();
    vbuf[t] = vreg;
    __syncthreads();
    G[((u64)h*64 + (63-j))*64 + t] = vreg;
    float pr = cv*vreg;
    #pragma unroll
    for (int m=1;m<64;m<<=1) pr += __shfl_xor(pr, m, 64);
    if (t==0) ks[h*64 + j] = pr;
    float nv = 0.f;
    #pragma unroll
    for (int p4=0;p4<16;p4++){
      float4 v4 = *(const float4*)&vbuf[p4*4];
      nv += rowr[p4*4+0]*v4.x + rowr[p4*4+1]*v4.y + rowr[p4*4+2]*v4.z + rowr[p4*4+3]*v4.w;
    }
    vreg = nv;
  }

  // w-iteration: M (uses column t of A_bar = y[])
  float wreg = cv;
  for (int j=0;j<64;j++){
    __syncthreads();
    wbuf[t] = wreg;
    __syncthreads();
    float nw = 0.f;
    #pragma unroll
    for (int p4=0;p4<16;p4++){
      float4 w4 = *(const float4*)&wbuf[p4*4];
      nw += y[p4*4+0]*w4.x + y[p4*4+1]*w4.y + y[p4*4+2]*w4.z + y[p4*4+3]*w4.w;
    }
    Mx[((u64)h*64 + j)*64 + t] = nw;
    wreg = nw;
  }
  __syncthreads();

  // P = A_bar^64 via 6 squarings (ping-pong Ab <-> Tb, ends in Ab)
  for (int sq=0; sq<6; sq++){
    float (*Src)[64] = (sq&1)? Tb : Ab;
    float (*Dst)[64] = (sq&1)? Ab : Tb;
    float scol[64];
    #pragma unroll
    for (int k=0;k<64;k++) scol[k] = Src[k][t];
    for (int i=0;i<64;i++){
      float acc = 0.f;
      #pragma unroll
      for (int k4=0;k4<16;k4++){
        float4 s4 = *(const float4*)&Src[i][k4*4];
        acc += s4.x*scol[k4*4+0] + s4.y*scol[k4*4+1] + s4.z*scol[k4*4+2] + s4.w*scol[k4*4+3];
      }
      Dst[i][t] = acc;
    }
    __syncthreads();
  }
  for (int i=0;i<64;i++) P[((u64)h*64 + i)*64 + t] = Ab[i][t];
}

// ---------------- K2: U[b][h][c][n] = sum_t xT[b,h,cT+t] * G[h][t][n] ----------------
__global__ __launch_bounds__(256) void k_proj_u(const float* __restrict__ xT, const float* __restrict__ G,
                          float* __restrict__ U){
  int h = blockIdx.x, bc0 = blockIdx.y*64;
  __shared__ __align__(16) float xs[64][65];
  __shared__ __align__(16) float gs[64][68];
  int tid = threadIdx.x;
  for (int i=tid;i<4096;i+=256){
    int t = i>>6, n = i&63;
    gs[t][n] = G[(u64)h*4096 + i];
  }
  for (int i=tid;i<4096;i+=256){
    int r = i>>6, t = i&63;
    int bc = bc0 + r, b = bc>>6, c = bc&63;
    xs[r][t] = xT[((u64)b*HCH + h)*LSEQ + c*64 + t];
  }
  __syncthreads();
  int tb = tid>>4, tn = tid&15;
  float acc[4][4] = {};
  #pragma unroll 8
  for (int t=0;t<64;t++){
    float4 g4 = *(const float4*)&gs[t][tn*4];
    #pragma unroll
    for (int r=0;r<4;r++){
      float xv = xs[tb*4+r][t];
      acc[r][0] += xv*g4.x; acc[r][1] += xv*g4.y; acc[r][2] += xv*g4.z; acc[r][3] += xv*g4.w;
    }
  }
  #pragma unroll
  for (int r=0;r<4;r++){
    int bc = bc0 + tb*4 + r, b = bc>>6, c = bc&63;
    float4 o4 = make_float4(acc[r][0],acc[r][1],acc[r][2],acc[r][3]);
    *(float4*)&U[(((u64)b*HCH + h)*NCHK + c)*NST + tn*4] = o4;
  }
}

// ---------------- K3: state scan over chunks ----------------
// S[b][h][c][:] = state BEFORE chunk c; s_c = P*s_{c-1} + u_c
__global__ __launch_bounds__(256) void k_scan(const float* __restrict__ U, const float* __restrict__ P,
                        float* __restrict__ S){
  int tid = threadIdx.x, lane = tid&63, wid = tid>>6;
  int bh = blockIdx.x*4 + wid;
  int b = bh>>7, h = bh&127;
  const float* Ph = P + (u64)h*4096;
  float prow[64];
  #pragma unroll
  for (int j4=0;j4<16;j4++){
    float4 p4 = *(const float4*)&Ph[lane*64 + j4*4];
    prow[j4*4+0]=p4.x; prow[j4*4+1]=p4.y; prow[j4*4+2]=p4.z; prow[j4*4+3]=p4.w;
  }
  const float* Ub = U + ((u64)b*HCH + h)*(NCHK*NST);
  float*       Sb = S + ((u64)b*HCH + h)*(NCHK*NST);
  float s = 0.f;
  for (int c=0;c<NCHK;c++){
    Sb[c*64 + lane] = s;
    float acc = Ub[c*64 + lane];
    #pragma unroll
    for (int j=0;j<64;j++){
      float sj = __uint_as_float(__builtin_amdgcn_readlane(__float_as_uint(s), j));
      acc += sj * prow[j];
    }
    s = acc;
  }
}

// ---------------- K4a: z = intra-conv + cross + D*x -> zT[b][h][l] ----------------
__global__ __launch_bounds__(256) void k_zmix(const float* __restrict__ xT, const float* __restrict__ S,
                        const float* __restrict__ Mx, const float* __restrict__ ks,
                        const float* __restrict__ D, float* __restrict__ zT){
  int h = blockIdx.x, bc0 = blockIdx.y*64;
  __shared__ __align__(16) float xs[64][65];
  __shared__ __align__(16) float ss[64][65];
  __shared__ __align__(16) float bb[128][68];
  __shared__ __align__(16) float kv[64];
  int tid = threadIdx.x;
  if (tid < 64) kv[tid] = ks[h*64 + tid];
  for (int i=tid;i<4096;i+=256){
    int r=i>>6, t=i&63;
    int bc=bc0+r, b=bc>>6, c=bc&63;
    xs[r][t] = xT[((u64)b*HCH + h)*LSEQ + c*64 + t];
    ss[r][t] = S[(((u64)b*HCH + h)*NCHK + c)*NST + t];
  }
  for (int i=tid;i<4096;i+=256){
    int t=i>>6, n=i&63;
    bb[64+n][t] = Mx[(u64)h*4096 + i];     // bb[64+n][t] = M[t][n]
  }
  __syncthreads();
  for (int i=tid;i<4096;i+=256){
    int j=i>>6, t=i&63;
    bb[j][t] = (t>=j)? kv[t-j] : 0.f;      // upper-tri Toeplitz of k
  }
  __syncthreads();
  int tb=tid>>4, tn=tid&15;
  float acc[4][4]={};
  #pragma unroll 4
  for (int kk=0;kk<64;kk++){
    float4 b4 = *(const float4*)&bb[kk][tn*4];
    #pragma unroll
    for (int r=0;r<4;r++){
      float av = xs[tb*4+r][kk];
      acc[r][0]+=av*b4.x; acc[r][1]+=av*b4.y; acc[r][2]+=av*b4.z; acc[r][3]+=av*b4.w;
    }
  }
  #pragma unroll 4
  for (int kk=0;kk<64;kk++){
    float4 b4 = *(const float4*)&bb[64+kk][tn*4];
    #pragma unroll
    for (int r=0;r<4;r++){
      float av = ss[tb*4+r][kk];
      acc[r][0]+=av*b4.x; acc[r][1]+=av*b4.y; acc[r][2]+=av*b4.z; acc[r][3]+=av*b4.w;
    }
  }
  float dv = D[h];
  #pragma unroll
  for (int r=0;r<4;r++){
    int bc=bc0+tb*4+r, b=bc>>6, c=bc&63;
    float4 o4;
    o4.x = acc[r][0] + dv*xs[tb*4+r][tn*4+0];
    o4.y = acc[r][1] + dv*xs[tb*4+r][tn*4+1];
    o4.z = acc[r][2] + dv*xs[tb*4+r][tn*4+2];
    o4.w = acc[r][3] + dv*xs[tb*4+r][tn*4+3];
    *(float4*)&zT[((u64)b*HCH + h)*LSEQ + c*64 + tn*4] = o4;
  }
}

// ---------------- K4b: out[b][l][o] = sum_h zT[b][h][l]*Wt[h][o] + bias[o] ----------------
__global__ __launch_bounds__(256) void k_out(const float* __restrict__ zT, const float* __restrict__ Wt,
                       const float* __restrict__ bias, float* __restrict__ out){
  int l0 = blockIdx.x*64, b = blockIdx.y;
  __shared__ __align__(16) float zl[128][64];
  int tid = threadIdx.x;
  for (int i=tid;i<8192;i+=256){
    int hh=i>>6, ll=i&63;
    zl[hh][ll] = zT[((u64)b*HCH + hh)*LSEQ + l0 + ll];
  }
  __syncthreads();
  int lane = tid&63, wid = tid>>6;
  int o = (wid&1)*64 + lane;
  int lq0 = (wid>>1)*32;
  float bo = bias[o];
  float acc[32];
  #pragma unroll
  for (int q=0;q<32;q++) acc[q] = bo;
  #pragma unroll 2
  for (int hh=0;hh<128;hh++){
    float wv = Wt[hh*NOUTD + o];
    #pragma unroll
    for (int q4=0;q4<8;q4++){
      float4 z4 = *(const float4*)&zl[hh][lq0 + q4*4];
      acc[q4*4+0] += wv*z4.x; acc[q4*4+1] += wv*z4.y; acc[q4*4+2] += wv*z4.z; acc[q4*4+3] += wv*z4.w;
    }
  }
  #pragma unroll
  for (int q=0;q<32;q++){
    out[((u64)b*LSEQ + l0 + lq0 + q)*NOUTD + o] = acc[q];
  }
}

extern "C" void kernel_launch(void* const* d_in, const int* in_sizes, int n_in,
                              void* d_out, int out_size, void* d_ws, size_t ws_size,
                              hipStream_t stream){
  const float* x      = (const float*)d_in[0];
  const float* A      = (const float*)d_in[1];
  const float* Bm     = (const float*)d_in[2];
  const float* Cm     = (const float*)d_in[3];
  const float* D      = (const float*)d_in[4];
  const float* log_dt = (const float*)d_in[5];
  const float* W      = (const float*)d_in[6];
  const float* bias   = (const float*)d_in[7];
  float* out = (float*)d_out;
  float* ws  = (float*)d_ws;

  float* xT = ws + OFF_XT;
  float* U  = ws + OFF_U;
  float* S  = ws + OFF_S;
  float* G  = ws + OFF_G;
  float* Mx = ws + OFF_M;
  float* P  = ws + OFF_P;
  float* ks = ws + OFF_K;
  float* Wt = ws + OFF_WT;
  float* zT = U;   // U dead after k_scan; reuse as zT

  hipLaunchKernelGGL(k_tr_x,   dim3(64,2,16), dim3(256), 0, stream, x, xT);
  hipLaunchKernelGGL(k_tr_w,   dim3(64),      dim3(256), 0, stream, W, Wt);
  hipLaunchKernelGGL(k_pre,    dim3(128),     dim3(64),  0, stream, A, Bm, Cm, log_dt, G, Mx, P, ks);
  hipLaunchKernelGGL(k_proj_u, dim3(128,16),  dim3(256), 0, stream, xT, G, U);
  hipLaunchKernelGGL(k_scan,   dim3(512),     dim3(256), 0, stream, U, P, S);
  hipLaunchKernelGGL(k_zmix,   dim3(128,16),  dim3(256), 0, stream, xT, S, Mx, ks, D, zT);
  hipLaunchKernelGGL(k_out,    dim3(64,16),   dim3(256), 0, stream, zT, Wt, bias, out);
}